// Round 4
// baseline (773.872 us; speedup 1.0000x reference)
//
#include <hip/hip_runtime.h>
#include <hip/hip_bf16.h>

#define B    16
#define NA   25200
#define NCH  85
#define NCLS 80
#define K    2048
#define CAP  8192
#define DET  300
#define TILE 128
#define SBASE  0x3FD0000000000000ULL   // bits of 0.25 (double)
#define SSHIFT 42                      // -> 2048 bins over (0.25, 1.0)

typedef unsigned long long u64;
typedef unsigned int u32;

__device__ __forceinline__ double dsig(float x) { return 1.0 / (1.0 + exp(-(double)x)); }
__device__ __forceinline__ float  fsig(float x) { return 1.0f / (1.0f + __expf(-x)); }

// ---- Pass 1: LDS-staged approximate f32 histogram (cut selection only).
// Exactness restored by k_cut's one-bin margin + k_collect's exact f64 compare.
__global__ void __launch_bounds__(256) k_hist(const float* __restrict__ head, int* __restrict__ hist) {
    __shared__ float rows[TILE * NCH];   // 43520 B
    __shared__ int h[2048];              // 8192 B
    for (int i = threadIdx.x; i < 2048; i += 256) h[i] = 0;
    int img = blockIdx.y;
    int a0 = blockIdx.x * TILE;
    int na = NA - a0; if (na > TILE) na = TILE;          // 128 or 112 (both %4==0)
    const float4* src = (const float4*)(head + ((size_t)img * NA + a0) * NCH);
    int nf4 = (na * NCH) >> 2;
    for (int i = threadIdx.x; i < nf4; i += 256) ((float4*)rows)[i] = src[i];
    __syncthreads();
    for (int t = threadIdx.x; t < na * 2; t += 256) {    // 2 threads per anchor
        int a = t >> 1; int c0 = (t & 1) * 40;
        float fo = fsig(rows[a * NCH + 4]);
        if (fo <= 0.25f) continue;                       // product <= sig(obj)
        for (int c = c0; c < c0 + 40; ++c) {
            float sc = fo * fsig(rows[a * NCH + 5 + c]);
            if (sc > 0.25f) {
                u64 bits = (u64)__double_as_longlong((double)sc);
                int b = (int)((bits - SBASE) >> SSHIFT);
                if (b > 2047) b = 2047;
                atomicAdd(&h[b], 1);
            }
        }
    }
    __syncthreads();
    for (int i = threadIdx.x; i < 2048; i += 256) {
        int v = h[i];
        if (v) atomicAdd(&hist[img * 2048 + i], v);
    }
}

// ---- Pass 2: wave-per-image parallel scan for cut bin (one-bin safety margin) ----
__global__ void __launch_bounds__(1024) k_cut(const int* __restrict__ hist, u64* __restrict__ cut) {
    int lane = threadIdx.x & 63;
    int img  = threadIdx.x >> 6;          // 16 waves = 16 images
    const int* h = hist + img * 2048;
    int cum = 0;
    u64 cb = 0;
    for (int chunk = 0; chunk < 32; ++chunk) {
        int b = 2047 - chunk * 64 - lane; // top-down order = lane ascending
        int v = h[b];
        int pfx = v;
        for (int d = 1; d < 64; d <<= 1) { int o = __shfl_up(pfx, d, 64); if (lane >= d) pfx += o; }
        u64 ball = __ballot(cum + pfx >= K);
        if (ball) {
            int fl = __ffsll((long long)ball) - 1;
            int bin = 2047 - chunk * 64 - fl;
            cb = (bin >= 1) ? (SBASE + ((u64)(bin - 1) << SSHIFT)) : 0ULL;
            break;
        }
        cum += __shfl(pfx, 63, 64);
    }
    if (lane == 0) cut[img] = cb;
}

// ---- Pass 3: obj-first collect. score <= sig(obj), so screen on obj alone;
// only ~0.2% of anchors touch their 80 class logits. Exact f64 decisions. ----
__global__ void __launch_bounds__(256) k_collect(const float* __restrict__ head, const u64* __restrict__ cut,
                          u32* __restrict__ cnt, u64* __restrict__ sb, u32* __restrict__ si) {
    int img = blockIdx.y;
    int a = blockIdx.x * 256 + threadIdx.x;
    if (a >= NA) return;
    const float* row = head + ((size_t)img * NA + a) * NCH;
    u64 cutb = cut[img];
    float cutf = cutb ? (float)__longlong_as_double((long long)cutb) : 0.25f;
    float pre = fmaxf(0.2489f, cutf * 0.999f);   // margin 1e-3 >> f32 sig err 1e-6
    float o = row[4];
    float fo = fsig(o);
    if (fo < pre) return;                        // upper bound fails -> whole anchor out
    double so = dsig(o);
    u64* sbi = sb + (size_t)img * CAP;
    u32* sii = si + (size_t)img * CAP;
    for (int c = 0; c < NCLS; ++c) {
        float cl = row[5 + c];
        float s32 = fo * fsig(cl);
        if (s32 < pre) continue;
        double sc = so * dsig(cl);               // exact f64 decision
        if (sc > 0.25) {
            u64 bits = (u64)__double_as_longlong(sc);
            if (bits >= cutb) {
                u32 pos = atomicAdd(&cnt[img], 1u);
                if (pos < CAP) { sbi[pos] = bits; sii[pos] = (u32)(a * NCLS + c); }
            }
        }
    }
}

// ---- Pass 4: per-image exact bitonic sort (desc score-bits, asc index) ----
__global__ void __launch_bounds__(1024) k_sort(const u32* __restrict__ cntArr, u64* __restrict__ sb, u32* __restrict__ si) {
    __shared__ u64 SA[4096];
    __shared__ u32 SI[4096];
    int img = blockIdx.x;
    int tid = threadIdx.x;
    u64* A = sb + (size_t)img * CAP;
    u32* I = si + (size_t)img * CAP;
    int cnt = (int)cntArr[img]; if (cnt > CAP) cnt = CAP;
    int n = K; while (n < cnt) n <<= 1;

    if (n <= 4096) {
        for (int i = tid; i < n; i += 1024) {
            SA[i] = (i < cnt) ? A[i] : 0ULL;
            SI[i] = (i < cnt) ? I[i] : 0xFFFFFFFFu;
        }
        __syncthreads();
        for (unsigned k = 2; k <= (unsigned)n; k <<= 1) {
            for (unsigned j = k >> 1; j > 0; j >>= 1) {
                for (unsigned i = tid; i < (unsigned)n; i += 1024) {
                    unsigned l = i ^ j;
                    if (l > i) {
                        u64 s1 = SA[i], s2 = SA[l];
                        u32 i1 = SI[i], i2 = SI[l];
                        bool before = (s1 > s2) || (s1 == s2 && i1 < i2);
                        bool up = ((i & k) == 0);
                        if (up != before) { SA[i] = s2; SA[l] = s1; SI[i] = i2; SI[l] = i1; }
                    }
                }
                __syncthreads();
            }
        }
        for (int i = tid; i < K; i += 1024) { A[i] = SA[i]; I[i] = SI[i]; }
    } else {
        for (int t = cnt + tid; t < n; t += 1024) { A[t] = 0ULL; I[t] = 0xFFFFFFFFu; }
        for (unsigned k = 2; k <= (unsigned)n; k <<= 1) {
            for (unsigned j = k >> 1; j > 0; j >>= 1) {
                __syncthreads();
                for (unsigned i = tid; i < (unsigned)n; i += 1024) {
                    unsigned l = i ^ j;
                    if (l > i) {
                        u64 s1 = A[i], s2 = A[l];
                        u32 i1 = I[i], i2 = I[l];
                        bool before = (s1 > s2) || (s1 == s2 && i1 < i2);
                        bool up = ((i & k) == 0);
                        if (up != before) { A[i] = s2; A[l] = s1; I[i] = i2; I[l] = i1; }
                    }
                }
            }
        }
    }
}

// ---- Pass 5: decode (f64) -> LDS offset boxes; bitmask greedy NMS with
// barriers only on kept i; popcount-rank emit. 1024 threads, 2 slots/thread. ----
__global__ void __launch_bounds__(1024) k_nms(const float* __restrict__ head,
        const float* __restrict__ grid, const float* __restrict__ ag, const float* __restrict__ stv,
        const u64* __restrict__ sb, const u32* __restrict__ si,
        float* __restrict__ out) {
    __shared__ double ob[K * 4];      // 65536 B: offset boxes (i-broadcast side)
    __shared__ u64 mask[32];          // keep bitmask, bit per slot
    __shared__ double red[16];        // per-wave max
    __shared__ double s_offb;
    __shared__ int wpfx[33];

    int img = blockIdx.x;
    int tid = threadIdx.x;
    const u64* sbi = sb + (size_t)img * CAP;
    const u32* sii = si + (size_t)img * CAP;

    // Phase A: decode 2 boxes/thread (exact f64), track max coordinate
    double bx0[4], bx1[4];
    int lab0 = 0, lab1 = 0;
    bool val0, val1;
    double lmax = -1e300;
    u64 s0 = sbi[tid], s1 = sbi[tid + 1024];
    val0 = (s0 != 0ULL); val1 = (s1 != 0ULL);
    #pragma unroll
    for (int q = 0; q < 2; ++q) {
        int t = tid + q * 1024;
        bool v = q ? val1 : val0;
        double* bq = q ? bx1 : bx0;
        bq[0] = bq[1] = bq[2] = bq[3] = 0.0;
        if (v) {
            u32 fi = sii[t];
            int a = (int)(fi / NCLS);
            int lb = (int)(fi % NCLS);
            if (q) lab1 = lb; else lab0 = lb;
            const float* row = head + ((size_t)img * NA + a) * NCH;
            double p0 = dsig(row[0]), p1 = dsig(row[1]), p2 = dsig(row[2]), p3 = dsig(row[3]);
            double st = (double)stv[a];
            double xc = (p0 * 2.0 - 0.5 + (double)grid[a * 2 + 0]) * st;
            double yc = (p1 * 2.0 - 0.5 + (double)grid[a * 2 + 1]) * st;
            double w = p2 * 2.0; w = (w * w) * (double)ag[a * 2 + 0];
            double h = p3 * 2.0; h = (h * h) * (double)ag[a * 2 + 1];
            bq[0] = xc - w * 0.5; bq[1] = yc - h * 0.5;
            bq[2] = xc + w * 0.5; bq[3] = yc + h * 0.5;
            lmax = fmax(lmax, fmax(fmax(bq[0], bq[1]), fmax(bq[2], bq[3])));
        }
    }
    // wave max-reduce -> block max
    for (int d = 1; d < 64; d <<= 1) lmax = fmax(lmax, __shfl_xor(lmax, d, 64));
    if ((tid & 63) == 0) red[tid >> 6] = lmax;
    // init keep mask via ballot (wave w covers slots [64w,64w+64) and [1024+64w,...))
    u64 b0m = __ballot(val0), b1m = __ballot(val1);
    if ((tid & 63) == 0) { mask[tid >> 6] = b0m; mask[16 + (tid >> 6)] = b1m; }
    __syncthreads();
    if (tid == 0) {
        double m = red[0];
        for (int wv = 1; wv < 16; ++wv) m = fmax(m, red[wv]);
        s_offb = m + 1.0;                 // (max(cand) + 1), np-exact
    }
    __syncthreads();
    double offb = s_offb;

    // offset boxes: registers (j side) + LDS (i side)
    double oB0[4], oB1[4], aR0, aR1;
    {
        double off0 = offb * (double)lab0;
        oB0[0] = bx0[0] + off0; oB0[1] = bx0[1] + off0;
        oB0[2] = bx0[2] + off0; oB0[3] = bx0[3] + off0;
        aR0 = (oB0[2] - oB0[0]) * (oB0[3] - oB0[1]);
        double off1 = offb * (double)lab1;
        oB1[0] = bx1[0] + off1; oB1[1] = bx1[1] + off1;
        oB1[2] = bx1[2] + off1; oB1[3] = bx1[3] + off1;
        aR1 = (oB1[2] - oB1[0]) * (oB1[3] - oB1[1]);
        ob[tid * 4 + 0] = oB0[0]; ob[tid * 4 + 1] = oB0[1];
        ob[tid * 4 + 2] = oB0[2]; ob[tid * 4 + 3] = oB0[3];
        ob[(tid + 1024) * 4 + 0] = oB1[0]; ob[(tid + 1024) * 4 + 1] = oB1[1];
        ob[(tid + 1024) * 4 + 2] = oB1[2]; ob[(tid + 1024) * 4 + 3] = oB1[3];
    }
    bool alive0 = val0, alive1 = val1;
    __syncthreads();

    // Greedy NMS: scan bitmask for next kept i (no barrier on skipped slots).
    // Safe: suppressions only clear bits > i, so every thread resolves the same i.
    int i = -1, kc = 0;
    while (true) {
        int start = i + 1;
        if (start >= K) break;
        int w = start >> 6;
        u64 m = mask[w] & (~0ULL << (start & 63));
        while (m == 0ULL) { if (++w >= 32) break; m = mask[w]; }
        if (w >= 32) break;
        i = (w << 6) + __ffsll((long long)m) - 1;
        ++kc;
        if (kc >= DET) break;             // later suppressions can't affect top-300
        double bi0 = ob[i * 4 + 0], bi1 = ob[i * 4 + 1];
        double bi2 = ob[i * 4 + 2], bi3 = ob[i * 4 + 3];
        double ai = (bi2 - bi0) * (bi3 - bi1);   // bit-exact recompute
        {
            double w_ = fmax(fmin(bi2, oB0[2]) - fmax(bi0, oB0[0]), 0.0);
            double h_ = fmax(fmin(bi3, oB0[3]) - fmax(bi1, oB0[1]), 0.0);
            double inter = w_ * h_;
            double iou = inter / (ai + aR0 - inter + 1e-7);
            if (alive0 && tid > i && iou > 0.45) {
                alive0 = false;
                atomicAnd(&mask[tid >> 6], ~(1ULL << (tid & 63)));
            }
        }
        {
            int sl = tid + 1024;
            double w_ = fmax(fmin(bi2, oB1[2]) - fmax(bi0, oB1[0]), 0.0);
            double h_ = fmax(fmin(bi3, oB1[3]) - fmax(bi1, oB1[1]), 0.0);
            double inter = w_ * h_;
            double iou = inter / (ai + aR1 - inter + 1e-7);
            if (alive1 && sl > i && iou > 0.45) {
                alive1 = false;
                atomicAnd(&mask[sl >> 6], ~(1ULL << (sl & 63)));
            }
        }
        __syncthreads();
    }
    __syncthreads();

    // popcount ranks + emit
    if (tid == 0) {
        int s = 0;
        for (int wv = 0; wv < 32; ++wv) { wpfx[wv] = s; s += __popcll(mask[wv]); }
        wpfx[32] = s;
    }
    __syncthreads();
    int total = wpfx[32]; if (total > DET) total = DET;

    float* bo  = out + (size_t)img * DET * 4;
    float* so_ = out + (size_t)B * DET * 4 + (size_t)img * DET;
    float* lo  = out + (size_t)B * DET * 5 + (size_t)img * DET;
    {
        int w = tid >> 6, bpos = tid & 63;
        if ((mask[w] >> bpos) & 1ULL) {
            int r = wpfx[w] + __popcll(mask[w] & ((1ULL << bpos) - 1ULL));
            if (r < DET) {
                bo[r * 4 + 0] = (float)bx0[0]; bo[r * 4 + 1] = (float)bx0[1];
                bo[r * 4 + 2] = (float)bx0[2]; bo[r * 4 + 3] = (float)bx0[3];
                so_[r] = (float)__longlong_as_double((long long)s0);
                lo[r] = (float)lab0;
            }
        }
    }
    {
        int sl = tid + 1024;
        int w = sl >> 6, bpos = sl & 63;
        if ((mask[w] >> bpos) & 1ULL) {
            int r = wpfx[w] + __popcll(mask[w] & ((1ULL << bpos) - 1ULL));
            if (r < DET) {
                bo[r * 4 + 0] = (float)bx1[0]; bo[r * 4 + 1] = (float)bx1[1];
                bo[r * 4 + 2] = (float)bx1[2]; bo[r * 4 + 3] = (float)bx1[3];
                so_[r] = (float)__longlong_as_double((long long)s1);
                lo[r] = (float)lab1;
            }
        }
    }
    if (tid >= total && tid < DET) {
        bo[tid * 4 + 0] = 0.f; bo[tid * 4 + 1] = 0.f;
        bo[tid * 4 + 2] = 0.f; bo[tid * 4 + 3] = 0.f;
        so_[tid] = -1.0f; lo[tid] = -1.0f;
    }
}

extern "C" void kernel_launch(void* const* d_in, const int* in_sizes, int n_in,
                              void* d_out, int out_size, void* d_ws, size_t ws_size,
                              hipStream_t stream) {
    const float* head = (const float*)d_in[0];   // [16,25200,85]
    const float* grid = (const float*)d_in[1];   // [25200,2]
    const float* ag   = (const float*)d_in[2];   // [25200,2]
    const float* stv  = (const float*)d_in[3];   // [25200,1]
    float* out = (float*)d_out;
    char* ws = (char*)d_ws;

    int*    hist = (int*)(ws + 0);               // 16*2048*4 = 131072
    u32*    cnt  = (u32*)(ws + 131072);          // 64
    u64*    cut  = (u64*)(ws + 131200);          // 128
    u64*    sb   = (u64*)(ws + 131328);          // 16*8192*8 = 1048576
    u32*    si   = (u32*)(ws + 1179904);         // 16*8192*4 = 524288 (end ~1.7MB)

    hipMemsetAsync(ws, 0, 131136, stream);       // zero hist + cnt each call

    k_hist   <<<dim3((NA + TILE - 1) / TILE, B), 256, 0, stream>>>(head, hist);
    k_cut    <<<1, 1024, 0, stream>>>(hist, cut);
    k_collect<<<dim3((NA + 255) / 256, B), 256, 0, stream>>>(head, cut, cnt, sb, si);
    k_sort   <<<B, 1024, 0, stream>>>(cnt, sb, si);
    k_nms    <<<B, 1024, 0, stream>>>(head, grid, ag, stv, sb, si, out);
}

// Round 5
// 657.055 us; speedup vs baseline: 1.1778x; 1.1778x over previous
//
#include <hip/hip_runtime.h>
#include <hip/hip_bf16.h>

#define B    16
#define NA   25200
#define NCH  85
#define NCLS 80
#define K    2048
#define CAP  4096
#define ACAP 4096
#define DET  300
#define TILE 128
#define NTILES 197                     // ceil(25200/128)
#define HBLK 16                        // hist blocks per image
#define SBASE  0x3FD0000000000000ULL   // bits of 0.25 (double)
#define SSHIFT 42                      // -> 2048 bins over (0.25, 1.0)

typedef unsigned long long u64;
typedef unsigned int u32;
typedef unsigned short u16;

__device__ __forceinline__ double dsig(float x) { return 1.0 / (1.0 + exp(-(double)x)); }
__device__ __forceinline__ float  fsig(float x) { return 1.0f / (1.0f + __expf(-x)); }

// ---- Pass 1: full sweep. Per-block partial histogram (plain stores, no global
// atomics) + per-anchor f32 max-score rounded UP to u16 (screen upper bound).
__global__ void __launch_bounds__(256) k_hist(const float* __restrict__ head,
                                              u32* __restrict__ phist, u16* __restrict__ smax16) {
    __shared__ float rows[TILE * NCH];     // 43520 B
    __shared__ int h[2048];                // 8192 B
    __shared__ float smaxT[TILE][2];       // 1024 B
    int tid = threadIdx.x;
    for (int i = tid; i < 2048; i += 256) h[i] = 0;
    int img = blockIdx.y;
    const float* ibase = head + (size_t)img * NA * NCH;

    for (int tile = blockIdx.x; tile < NTILES; tile += HBLK) {
        int a0 = tile * TILE;
        int na = NA - a0; if (na > TILE) na = TILE;      // 128 or 112 (both *85 %4==0)
        const float4* src = (const float4*)(ibase + (size_t)a0 * NCH);
        int nf4 = (na * NCH) >> 2;
        __syncthreads();                                 // prev writeback done
        for (int i = tid; i < nf4; i += 256) ((float4*)rows)[i] = src[i];
        __syncthreads();
        for (int t = tid; t < 2 * na; t += 256) {        // 2 threads per anchor
            int a = t >> 1, half = t & 1;
            float fo = fsig(rows[a * NCH + 4]);
            float lm = 0.0f;
            if (fo > 0.25f) {                            // score <= sig(obj)
                int c0 = half * 40;
                for (int c = c0; c < c0 + 40; ++c) {
                    float sc = fo * fsig(rows[a * NCH + 5 + c]);
                    lm = fmaxf(lm, sc);
                    if (sc > 0.25f) {
                        u64 bits = (u64)__double_as_longlong((double)sc);
                        int bb = (int)((bits - SBASE) >> SSHIFT);
                        if (bb > 2047) bb = 2047;
                        atomicAdd(&h[bb], 1);
                    }
                }
            }
            smaxT[a][half] = lm;
        }
        __syncthreads();
        for (int t = tid; t < na; t += 256) {
            float m = fmaxf(smaxT[t][0], smaxT[t][1]);
            u32 mb = __float_as_uint(m);
            smax16[(size_t)img * NA + a0 + t] = (u16)((mb + 0xFFFFu) >> 16);  // round UP
        }
    }
    __syncthreads();
    u32* dst = phist + ((size_t)img * HBLK + blockIdx.x) * 2048;
    for (int i = tid; i < 2048; i += 256) dst[i] = (u32)h[i];
}

// ---- Pass 1b: reduce 16 partial histograms -> final (coalesced, no atomics) ----
__global__ void __launch_bounds__(256) k_redhist(const u32* __restrict__ phist, int* __restrict__ hist) {
    int g = blockIdx.x * 256 + threadIdx.x;      // 16*2048 total
    int img = g >> 11, bin = g & 2047;
    u32 s = 0;
    #pragma unroll
    for (int p = 0; p < HBLK; ++p) s += phist[((size_t)img * HBLK + p) * 2048 + bin];
    hist[g] = (int)s;
}

// ---- Pass 2: cut bin (one-bin safety margin); all bins preloaded to registers ----
__global__ void __launch_bounds__(1024) k_cut(const int* __restrict__ hist, u64* __restrict__ cut) {
    int lane = threadIdx.x & 63;
    int img  = threadIdx.x >> 6;                 // 16 waves = 16 images
    const int* h = hist + img * 2048;
    int v[32];
    #pragma unroll
    for (int ch = 0; ch < 32; ++ch) v[ch] = h[2047 - ch * 64 - lane];
    int cum = 0; u64 cb = 0;
    #pragma unroll
    for (int ch = 0; ch < 32; ++ch) {
        int pfx = v[ch];
        for (int d = 1; d < 64; d <<= 1) { int o = __shfl_up(pfx, d, 64); if (lane >= d) pfx += o; }
        u64 ball = __ballot(cum + pfx >= K);
        if (ball) {
            int fl = __ffsll((long long)ball) - 1;
            int bin = 2047 - ch * 64 - fl;
            cb = (bin >= 1) ? (SBASE + ((u64)(bin - 1) << SSHIFT)) : 0ULL;
            break;
        }
        cum += __shfl(pfx, 63, 64);
    }
    if (lane == 0) cut[img] = cb;
}

// ---- Pass 3a: screen anchors by smax upper bound; compact survivor list ----
__global__ void __launch_bounds__(256) k_screen(const u16* __restrict__ smax16, const u64* __restrict__ cut,
                                                u32* __restrict__ cntA, int* __restrict__ alist) {
    __shared__ int lcnt, lbase, buf[256];
    int img = blockIdx.y;
    int a = blockIdx.x * 256 + threadIdx.x;
    if (threadIdx.x == 0) lcnt = 0;
    __syncthreads();
    u64 cutb = cut[img];
    float cutf = cutb ? (float)__longlong_as_double((long long)cutb) : 0.25f;
    float pre = fmaxf(0.2489f, cutf * 0.999f);
    if (a < NA) {
        float fup = __uint_as_float(((u32)smax16[(size_t)img * NA + a]) << 16);
        if (fup >= pre) buf[atomicAdd(&lcnt, 1)] = a;
    }
    __syncthreads();
    if (threadIdx.x == 0 && lcnt) lbase = atomicAdd(&cntA[img], (u32)lcnt);
    __syncthreads();
    for (int i = threadIdx.x; i < lcnt; i += 256) {
        int pos = lbase + i;
        if (pos < ACAP) alist[img * ACAP + pos] = buf[i];
    }
}

// ---- Pass 3b: lane-parallel (anchor,class) pairs; exact f64 decisions ----
__global__ void __launch_bounds__(256) k_pairs(const float* __restrict__ head, const u64* __restrict__ cut,
                                               const u32* __restrict__ cntA, const int* __restrict__ alist,
                                               u32* __restrict__ cnt, u64* __restrict__ sb, u32* __restrict__ si) {
    int img = blockIdx.y;
    u64 cutb = cut[img];
    float cutf = cutb ? (float)__longlong_as_double((long long)cutb) : 0.25f;
    float pre = fmaxf(0.2489f, cutf * 0.999f);
    int nsur = (int)cntA[img]; if (nsur > ACAP) nsur = ACAP;
    int npairs = nsur * NCLS;
    u64* sbi = sb + (size_t)img * CAP;
    u32* sii = si + (size_t)img * CAP;
    const float* ibase = head + (size_t)img * NA * NCH;
    for (int p = blockIdx.x * 256 + threadIdx.x; p < npairs; p += 32 * 256) {
        int ai = (int)((u32)p / NCLS);
        int c  = p - ai * NCLS;
        int a  = alist[img * ACAP + ai];
        const float* row = ibase + (size_t)a * NCH;
        float o = row[4], cl = row[5 + c];
        float s32 = fsig(o) * fsig(cl);
        if (s32 < pre) continue;
        double sc = dsig(o) * dsig(cl);            // exact f64 decision
        if (sc > 0.25) {
            u64 bits = (u64)__double_as_longlong(sc);
            if (bits >= cutb) {
                u32 pos = atomicAdd(&cnt[img], 1u);
                if (pos < CAP) { sbi[pos] = bits; sii[pos] = (u32)(a * NCLS + c); }
            }
        }
    }
}

// ---- Pass 4: per-image exact bitonic sort in LDS (desc bits, asc index) ----
__global__ void __launch_bounds__(1024) k_sort(const u32* __restrict__ cntArr, u64* __restrict__ sb, u32* __restrict__ si) {
    __shared__ u64 SA[4096];
    __shared__ u32 SI[4096];
    int img = blockIdx.x;
    int tid = threadIdx.x;
    u64* A = sb + (size_t)img * CAP;
    u32* I = si + (size_t)img * CAP;
    int cnt = (int)cntArr[img]; if (cnt > CAP) cnt = CAP;
    int n = K; while (n < cnt) n <<= 1;            // 2048 or 4096
    for (int i = tid; i < n; i += 1024) {
        SA[i] = (i < cnt) ? A[i] : 0ULL;
        SI[i] = (i < cnt) ? I[i] : 0xFFFFFFFFu;
    }
    __syncthreads();
    for (unsigned k = 2; k <= (unsigned)n; k <<= 1) {
        for (unsigned j = k >> 1; j > 0; j >>= 1) {
            for (unsigned i = tid; i < (unsigned)n; i += 1024) {
                unsigned l = i ^ j;
                if (l > i) {
                    u64 s1 = SA[i], s2 = SA[l];
                    u32 i1 = SI[i], i2 = SI[l];
                    bool before = (s1 > s2) || (s1 == s2 && i1 < i2);
                    bool up = ((i & k) == 0);
                    if (up != before) { SA[i] = s2; SA[l] = s1; SI[i] = i2; SI[l] = i1; }
                }
            }
            __syncthreads();
        }
    }
    for (int i = tid; i < K; i += 1024) { A[i] = SA[i]; I[i] = SI[i]; }
}

// ---- Pass 5: decode (f64) -> LDS offset boxes; bitmask greedy NMS; popcount emit ----
__global__ void __launch_bounds__(1024) k_nms(const float* __restrict__ head,
        const float* __restrict__ grid, const float* __restrict__ ag, const float* __restrict__ stv,
        const u64* __restrict__ sb, const u32* __restrict__ si,
        float* __restrict__ out) {
    __shared__ double ob[K * 4];      // 65536 B
    __shared__ u64 mask[32];
    __shared__ double red[16];
    __shared__ double s_offb;
    __shared__ int wpfx[33];

    int img = blockIdx.x;
    int tid = threadIdx.x;
    const u64* sbi = sb + (size_t)img * CAP;
    const u32* sii = si + (size_t)img * CAP;

    double bx0[4], bx1[4];
    int lab0 = 0, lab1 = 0;
    bool val0, val1;
    double lmax = -1e300;
    u64 s0 = sbi[tid], s1 = sbi[tid + 1024];
    val0 = (s0 != 0ULL); val1 = (s1 != 0ULL);
    #pragma unroll
    for (int q = 0; q < 2; ++q) {
        int t = tid + q * 1024;
        bool v = q ? val1 : val0;
        double* bq = q ? bx1 : bx0;
        bq[0] = bq[1] = bq[2] = bq[3] = 0.0;
        if (v) {
            u32 fi = sii[t];
            int a = (int)(fi / NCLS);
            int lb = (int)(fi % NCLS);
            if (q) lab1 = lb; else lab0 = lb;
            const float* row = head + ((size_t)img * NA + a) * NCH;
            double p0 = dsig(row[0]), p1 = dsig(row[1]), p2 = dsig(row[2]), p3 = dsig(row[3]);
            double st = (double)stv[a];
            double xc = (p0 * 2.0 - 0.5 + (double)grid[a * 2 + 0]) * st;
            double yc = (p1 * 2.0 - 0.5 + (double)grid[a * 2 + 1]) * st;
            double w = p2 * 2.0; w = (w * w) * (double)ag[a * 2 + 0];
            double h = p3 * 2.0; h = (h * h) * (double)ag[a * 2 + 1];
            bq[0] = xc - w * 0.5; bq[1] = yc - h * 0.5;
            bq[2] = xc + w * 0.5; bq[3] = yc + h * 0.5;
            lmax = fmax(lmax, fmax(fmax(bq[0], bq[1]), fmax(bq[2], bq[3])));
        }
    }
    for (int d = 1; d < 64; d <<= 1) lmax = fmax(lmax, __shfl_xor(lmax, d, 64));
    if ((tid & 63) == 0) red[tid >> 6] = lmax;
    u64 b0m = __ballot(val0), b1m = __ballot(val1);
    if ((tid & 63) == 0) { mask[tid >> 6] = b0m; mask[16 + (tid >> 6)] = b1m; }
    __syncthreads();
    if (tid == 0) {
        double m = red[0];
        for (int wv = 1; wv < 16; ++wv) m = fmax(m, red[wv]);
        s_offb = m + 1.0;
    }
    __syncthreads();
    double offb = s_offb;

    double oB0[4], oB1[4], aR0, aR1;
    {
        double off0 = offb * (double)lab0;
        oB0[0] = bx0[0] + off0; oB0[1] = bx0[1] + off0;
        oB0[2] = bx0[2] + off0; oB0[3] = bx0[3] + off0;
        aR0 = (oB0[2] - oB0[0]) * (oB0[3] - oB0[1]);
        double off1 = offb * (double)lab1;
        oB1[0] = bx1[0] + off1; oB1[1] = bx1[1] + off1;
        oB1[2] = bx1[2] + off1; oB1[3] = bx1[3] + off1;
        aR1 = (oB1[2] - oB1[0]) * (oB1[3] - oB1[1]);
        ob[tid * 4 + 0] = oB0[0]; ob[tid * 4 + 1] = oB0[1];
        ob[tid * 4 + 2] = oB0[2]; ob[tid * 4 + 3] = oB0[3];
        ob[(tid + 1024) * 4 + 0] = oB1[0]; ob[(tid + 1024) * 4 + 1] = oB1[1];
        ob[(tid + 1024) * 4 + 2] = oB1[2]; ob[(tid + 1024) * 4 + 3] = oB1[3];
    }
    bool alive0 = val0, alive1 = val1;
    __syncthreads();

    int i = -1, kc = 0;
    while (true) {
        int start = i + 1;
        if (start >= K) break;
        int w = start >> 6;
        u64 m = mask[w] & (~0ULL << (start & 63));
        while (m == 0ULL) { if (++w >= 32) break; m = mask[w]; }
        if (w >= 32) break;
        i = (w << 6) + __ffsll((long long)m) - 1;
        ++kc;
        if (kc >= DET) break;
        double bi0 = ob[i * 4 + 0], bi1 = ob[i * 4 + 1];
        double bi2 = ob[i * 4 + 2], bi3 = ob[i * 4 + 3];
        double ai = (bi2 - bi0) * (bi3 - bi1);
        {
            double w_ = fmax(fmin(bi2, oB0[2]) - fmax(bi0, oB0[0]), 0.0);
            double h_ = fmax(fmin(bi3, oB0[3]) - fmax(bi1, oB0[1]), 0.0);
            double inter = w_ * h_;
            double iou = inter / (ai + aR0 - inter + 1e-7);
            if (alive0 && tid > i && iou > 0.45) {
                alive0 = false;
                atomicAnd(&mask[tid >> 6], ~(1ULL << (tid & 63)));
            }
        }
        {
            int sl = tid + 1024;
            double w_ = fmax(fmin(bi2, oB1[2]) - fmax(bi0, oB1[0]), 0.0);
            double h_ = fmax(fmin(bi3, oB1[3]) - fmax(bi1, oB1[1]), 0.0);
            double inter = w_ * h_;
            double iou = inter / (ai + aR1 - inter + 1e-7);
            if (alive1 && sl > i && iou > 0.45) {
                alive1 = false;
                atomicAnd(&mask[sl >> 6], ~(1ULL << (sl & 63)));
            }
        }
        __syncthreads();
    }
    __syncthreads();

    if (tid == 0) {
        int s = 0;
        for (int wv = 0; wv < 32; ++wv) { wpfx[wv] = s; s += __popcll(mask[wv]); }
        wpfx[32] = s;
    }
    __syncthreads();
    int total = wpfx[32]; if (total > DET) total = DET;

    float* bo  = out + (size_t)img * DET * 4;
    float* so_ = out + (size_t)B * DET * 4 + (size_t)img * DET;
    float* lo  = out + (size_t)B * DET * 5 + (size_t)img * DET;
    {
        int w = tid >> 6, bpos = tid & 63;
        if ((mask[w] >> bpos) & 1ULL) {
            int r = wpfx[w] + __popcll(mask[w] & ((1ULL << bpos) - 1ULL));
            if (r < DET) {
                bo[r * 4 + 0] = (float)bx0[0]; bo[r * 4 + 1] = (float)bx0[1];
                bo[r * 4 + 2] = (float)bx0[2]; bo[r * 4 + 3] = (float)bx0[3];
                so_[r] = (float)__longlong_as_double((long long)s0);
                lo[r] = (float)lab0;
            }
        }
    }
    {
        int sl = tid + 1024;
        int w = sl >> 6, bpos = sl & 63;
        if ((mask[w] >> bpos) & 1ULL) {
            int r = wpfx[w] + __popcll(mask[w] & ((1ULL << bpos) - 1ULL));
            if (r < DET) {
                bo[r * 4 + 0] = (float)bx1[0]; bo[r * 4 + 1] = (float)bx1[1];
                bo[r * 4 + 2] = (float)bx1[2]; bo[r * 4 + 3] = (float)bx1[3];
                so_[r] = (float)__longlong_as_double((long long)s1);
                lo[r] = (float)lab1;
            }
        }
    }
    if (tid >= total && tid < DET) {
        bo[tid * 4 + 0] = 0.f; bo[tid * 4 + 1] = 0.f;
        bo[tid * 4 + 2] = 0.f; bo[tid * 4 + 3] = 0.f;
        so_[tid] = -1.0f; lo[tid] = -1.0f;
    }
}

extern "C" void kernel_launch(void* const* d_in, const int* in_sizes, int n_in,
                              void* d_out, int out_size, void* d_ws, size_t ws_size,
                              hipStream_t stream) {
    const float* head = (const float*)d_in[0];   // [16,25200,85]
    const float* grid = (const float*)d_in[1];   // [25200,2]
    const float* ag   = (const float*)d_in[2];   // [25200,2]
    const float* stv  = (const float*)d_in[3];   // [25200,1]
    float* out = (float*)d_out;
    char* ws = (char*)d_ws;

    // Layout (sb/si alias phist, which is dead after k_redhist):
    u32* phist  = (u32*)(ws + 0);                // 16*16*2048*4 = 2,097,152
    u64* sb     = (u64*)(ws + 0);                // 16*4096*8 = 524,288  (alias)
    u32* si     = (u32*)(ws + 524288);           // 16*4096*4 = 262,144  (alias)
    int* hist   = (int*)(ws + 2097152);          // 131,072
    u32* cnt    = (u32*)(ws + 2228224);          // 64
    u32* cntA   = (u32*)(ws + 2228288);          // 64
    u64* cut    = (u64*)(ws + 2228352);          // 128
    u16* smax16 = (u16*)(ws + 2228480);          // 16*25200*2 = 806,400
    int* alist  = (int*)(ws + 3034880);          // 16*4096*4 = 262,144  (end 3,297,024)

    hipMemsetAsync(ws + 2228224, 0, 128, stream);   // cnt + cntA

    k_hist   <<<dim3(HBLK, B), 256, 0, stream>>>(head, phist, smax16);
    k_redhist<<<(B * 2048) / 256, 256, 0, stream>>>(phist, hist);
    k_cut    <<<1, 1024, 0, stream>>>(hist, cut);
    k_screen <<<dim3((NA + 255) / 256, B), 256, 0, stream>>>(smax16, cut, cntA, alist);
    k_pairs  <<<dim3(32, B), 256, 0, stream>>>(head, cut, cntA, alist, cnt, sb, si);
    k_sort   <<<B, 1024, 0, stream>>>(cnt, sb, si);
    k_nms    <<<B, 1024, 0, stream>>>(head, grid, ag, stv, sb, si, out);
}

// Round 6
// 595.593 us; speedup vs baseline: 1.2993x; 1.1032x over previous
//
#include <hip/hip_runtime.h>
#include <hip/hip_bf16.h>

#define B    16
#define NA   25200
#define NCH  85
#define NCLS 80
#define K    2048
#define CAP  4096
#define ACAP 4096
#define DET  300
#define TILE 64
#define NTILES 394                     // ceil(25200/64)
#define SBASE  0x3FD0000000000000ULL   // bits of 0.25 (double)
#define SSHIFT 42                      // -> 2048 bins over (0.25, 1.0)

typedef unsigned long long u64;
typedef unsigned int u32;
typedef unsigned short u16;

__device__ __forceinline__ double dsig(float x) { return 1.0 / (1.0 + exp(-(double)x)); }
__device__ __forceinline__ float  fsig(float x) { return 1.0f / (1.0f + __expf(-x)); }

// ---- Pass 1: full sweep. Per-block partial histogram (plain stores) +
// per-anchor f32 max-score rounded UP to u16. 4 tasks/anchor (20 classes each).
__global__ void __launch_bounds__(256) k_hist(const float* __restrict__ head,
                                              u32* __restrict__ phist, u16* __restrict__ smax16) {
    __shared__ float rows[TILE * NCH];     // 21760 B
    __shared__ int h[2048];                // 8192 B
    __shared__ float smaxT[TILE][4];       // 1024 B
    int tid = threadIdx.x;
    int hblk = gridDim.x;
    for (int i = tid; i < 2048; i += 256) h[i] = 0;
    int img = blockIdx.y;
    const float* ibase = head + (size_t)img * NA * NCH;

    for (int tile = blockIdx.x; tile < NTILES; tile += hblk) {
        int a0 = tile * TILE;
        int na = NA - a0; if (na > TILE) na = TILE;      // 64 or 48 (na*85 %4==0)
        const float4* src = (const float4*)(ibase + (size_t)a0 * NCH);
        int nf4 = (na * NCH) >> 2;
        __syncthreads();                                 // prev tile fully consumed
        for (int i = tid; i < nf4; i += 256) ((float4*)rows)[i] = src[i];
        __syncthreads();
        for (int t = tid; t < 4 * na; t += 256) {        // 4 threads per anchor
            int a = t >> 2, q = t & 3;
            float fo = fsig(rows[a * NCH + 4]);
            float lm = 0.0f;
            if (fo > 0.25f) {                            // score <= sig(obj)
                int c0 = q * 20;
                for (int c = c0; c < c0 + 20; ++c) {
                    float sc = fo * fsig(rows[a * NCH + 5 + c]);
                    lm = fmaxf(lm, sc);
                    if (sc > 0.25f) {
                        u64 bits = (u64)__double_as_longlong((double)sc);
                        int bb = (int)((bits - SBASE) >> SSHIFT);
                        if (bb > 2047) bb = 2047;
                        atomicAdd(&h[bb], 1);
                    }
                }
            }
            smaxT[a][q] = lm;
        }
        __syncthreads();
        for (int t = tid; t < na; t += 256) {
            float m = fmaxf(fmaxf(smaxT[t][0], smaxT[t][1]), fmaxf(smaxT[t][2], smaxT[t][3]));
            u32 mb = __float_as_uint(m);
            smax16[(size_t)img * NA + a0 + t] = (u16)((mb + 0xFFFFu) >> 16);  // round UP
        }
    }
    __syncthreads();
    u32* dst = phist + ((size_t)img * hblk + blockIdx.x) * 2048;
    for (int i = tid; i < 2048; i += 256) dst[i] = (u32)h[i];
}

// ---- Pass 2: fused partial-hist reduce + cut-bin search (one block per image) ----
__global__ void __launch_bounds__(256) k_redcut(const u32* __restrict__ phist,
                                                u64* __restrict__ cut, int hblk) {
    __shared__ int h[2048];
    int img = blockIdx.x, tid = threadIdx.x;
    for (int bin = tid; bin < 2048; bin += 256) {
        u32 s = 0;
        for (int p = 0; p < hblk; ++p) s += phist[((size_t)img * hblk + p) * 2048 + bin];
        h[bin] = (int)s;
    }
    __syncthreads();
    if (tid < 64) {                       // wave 0 does the top-down scan
        int lane = tid;
        int cum = 0; u64 cb = 0;
        for (int ch = 0; ch < 32; ++ch) {
            int pfx = h[2047 - ch * 64 - lane];
            for (int d = 1; d < 64; d <<= 1) { int o = __shfl_up(pfx, d, 64); if (lane >= d) pfx += o; }
            u64 ball = __ballot(cum + pfx >= K);
            if (ball) {
                int fl = __ffsll((long long)ball) - 1;
                int bin = 2047 - ch * 64 - fl;
                cb = (bin >= 1) ? (SBASE + ((u64)(bin - 1) << SSHIFT)) : 0ULL;  // one-bin margin
                break;
            }
            cum += __shfl(pfx, 63, 64);
        }
        if (lane == 0) cut[img] = cb;
    }
}

// ---- Pass 3a: screen anchors by smax upper bound; compact survivor list ----
__global__ void __launch_bounds__(256) k_screen(const u16* __restrict__ smax16, const u64* __restrict__ cut,
                                                u32* __restrict__ cntA, int* __restrict__ alist) {
    __shared__ int lcnt, lbase, buf[256];
    int img = blockIdx.y;
    int a = blockIdx.x * 256 + threadIdx.x;
    if (threadIdx.x == 0) lcnt = 0;
    __syncthreads();
    u64 cutb = cut[img];
    float cutf = cutb ? (float)__longlong_as_double((long long)cutb) : 0.25f;
    float pre = fmaxf(0.2489f, cutf * 0.999f);
    if (a < NA) {
        float fup = __uint_as_float(((u32)smax16[(size_t)img * NA + a]) << 16);
        if (fup >= pre) buf[atomicAdd(&lcnt, 1)] = a;
    }
    __syncthreads();
    if (threadIdx.x == 0 && lcnt) lbase = atomicAdd(&cntA[img], (u32)lcnt);
    __syncthreads();
    for (int i = threadIdx.x; i < lcnt; i += 256) {
        int pos = lbase + i;
        if (pos < ACAP) alist[img * ACAP + pos] = buf[i];
    }
}

// ---- Pass 3b: lane-parallel (anchor,class) pairs; exact f64 decisions ----
__global__ void __launch_bounds__(256) k_pairs(const float* __restrict__ head, const u64* __restrict__ cut,
                                               const u32* __restrict__ cntA, const int* __restrict__ alist,
                                               u32* __restrict__ cnt, u64* __restrict__ sb, u32* __restrict__ si) {
    int img = blockIdx.y;
    u64 cutb = cut[img];
    float cutf = cutb ? (float)__longlong_as_double((long long)cutb) : 0.25f;
    float pre = fmaxf(0.2489f, cutf * 0.999f);
    int nsur = (int)cntA[img]; if (nsur > ACAP) nsur = ACAP;
    int npairs = nsur * NCLS;
    u64* sbi = sb + (size_t)img * CAP;
    u32* sii = si + (size_t)img * CAP;
    const float* ibase = head + (size_t)img * NA * NCH;
    for (int p = blockIdx.x * 256 + threadIdx.x; p < npairs; p += 32 * 256) {
        int ai = (int)((u32)p / NCLS);
        int c  = p - ai * NCLS;
        int a  = alist[img * ACAP + ai];
        const float* row = ibase + (size_t)a * NCH;
        float o = row[4], cl = row[5 + c];
        float s32 = fsig(o) * fsig(cl);
        if (s32 < pre) continue;
        double sc = dsig(o) * dsig(cl);            // exact f64 decision
        if (sc > 0.25) {
            u64 bits = (u64)__double_as_longlong(sc);
            if (bits >= cutb) {
                u32 pos = atomicAdd(&cnt[img], 1u);
                if (pos < CAP) { sbi[pos] = bits; sii[pos] = (u32)(a * NCLS + c); }
            }
        }
    }
}

// ---- Pass 4: per-image exact bitonic sort in LDS (desc bits, asc index) ----
__global__ void __launch_bounds__(1024) k_sort(const u32* __restrict__ cntArr, u64* __restrict__ sb, u32* __restrict__ si) {
    __shared__ u64 SA[4096];
    __shared__ u32 SI[4096];
    int img = blockIdx.x;
    int tid = threadIdx.x;
    u64* A = sb + (size_t)img * CAP;
    u32* I = si + (size_t)img * CAP;
    int cnt = (int)cntArr[img]; if (cnt > CAP) cnt = CAP;
    int n = K; while (n < cnt) n <<= 1;            // 2048 or 4096
    for (int i = tid; i < n; i += 1024) {
        SA[i] = (i < cnt) ? A[i] : 0ULL;
        SI[i] = (i < cnt) ? I[i] : 0xFFFFFFFFu;
    }
    __syncthreads();
    for (unsigned k = 2; k <= (unsigned)n; k <<= 1) {
        for (unsigned j = k >> 1; j > 0; j >>= 1) {
            for (unsigned i = tid; i < (unsigned)n; i += 1024) {
                unsigned l = i ^ j;
                if (l > i) {
                    u64 s1 = SA[i], s2 = SA[l];
                    u32 i1 = SI[i], i2 = SI[l];
                    bool before = (s1 > s2) || (s1 == s2 && i1 < i2);
                    bool up = ((i & k) == 0);
                    if (up != before) { SA[i] = s2; SA[l] = s1; SI[i] = i2; SI[l] = i1; }
                }
            }
            __syncthreads();
        }
    }
    for (int i = tid; i < K; i += 1024) { A[i] = SA[i]; I[i] = SI[i]; }
}

// ---- Pass 5: decode (f64) -> LDS offset boxes; bitmask greedy NMS with word
// summary (O(1) next-kept scan); mul-compare IoU (no f64 div); popcount emit. ----
__global__ void __launch_bounds__(1024) k_nms(const float* __restrict__ head,
        const float* __restrict__ grid, const float* __restrict__ ag, const float* __restrict__ stv,
        const u64* __restrict__ sb, const u32* __restrict__ si,
        float* __restrict__ out) {
    __shared__ double ob[K * 4];      // 65536 B
    __shared__ u64 mask[32];
    __shared__ u32 wsum;              // bit w set iff mask[w] != 0
    __shared__ double red[16];
    __shared__ double s_offb;
    __shared__ int wpfx[33];

    int img = blockIdx.x;
    int tid = threadIdx.x;
    const u64* sbi = sb + (size_t)img * CAP;
    const u32* sii = si + (size_t)img * CAP;

    double bx0[4], bx1[4];
    int lab0 = 0, lab1 = 0;
    bool val0, val1;
    double lmax = -1e300;
    u64 s0 = sbi[tid], s1 = sbi[tid + 1024];
    val0 = (s0 != 0ULL); val1 = (s1 != 0ULL);
    #pragma unroll
    for (int q = 0; q < 2; ++q) {
        int t = tid + q * 1024;
        bool v = q ? val1 : val0;
        double* bq = q ? bx1 : bx0;
        bq[0] = bq[1] = bq[2] = bq[3] = 0.0;
        if (v) {
            u32 fi = sii[t];
            int a = (int)(fi / NCLS);
            int lb = (int)(fi % NCLS);
            if (q) lab1 = lb; else lab0 = lb;
            const float* row = head + ((size_t)img * NA + a) * NCH;
            double p0 = dsig(row[0]), p1 = dsig(row[1]), p2 = dsig(row[2]), p3 = dsig(row[3]);
            double st = (double)stv[a];
            double xc = (p0 * 2.0 - 0.5 + (double)grid[a * 2 + 0]) * st;
            double yc = (p1 * 2.0 - 0.5 + (double)grid[a * 2 + 1]) * st;
            double w = p2 * 2.0; w = (w * w) * (double)ag[a * 2 + 0];
            double h = p3 * 2.0; h = (h * h) * (double)ag[a * 2 + 1];
            bq[0] = xc - w * 0.5; bq[1] = yc - h * 0.5;
            bq[2] = xc + w * 0.5; bq[3] = yc + h * 0.5;
            lmax = fmax(lmax, fmax(fmax(bq[0], bq[1]), fmax(bq[2], bq[3])));
        }
    }
    for (int d = 1; d < 64; d <<= 1) lmax = fmax(lmax, __shfl_xor(lmax, d, 64));
    if ((tid & 63) == 0) red[tid >> 6] = lmax;
    u64 b0m = __ballot(val0), b1m = __ballot(val1);
    if ((tid & 63) == 0) { mask[tid >> 6] = b0m; mask[16 + (tid >> 6)] = b1m; }
    if (tid == 0) wsum = 0;
    __syncthreads();
    if (tid < 32) { if (mask[tid]) atomicOr(&wsum, 1u << tid); }
    if (tid == 0) {
        double m = red[0];
        for (int wv = 1; wv < 16; ++wv) m = fmax(m, red[wv]);
        s_offb = m + 1.0;
    }
    __syncthreads();
    double offb = s_offb;

    double oB0[4], oB1[4], aR0, aR1;
    {
        double off0 = offb * (double)lab0;
        oB0[0] = bx0[0] + off0; oB0[1] = bx0[1] + off0;
        oB0[2] = bx0[2] + off0; oB0[3] = bx0[3] + off0;
        aR0 = (oB0[2] - oB0[0]) * (oB0[3] - oB0[1]);
        double off1 = offb * (double)lab1;
        oB1[0] = bx1[0] + off1; oB1[1] = bx1[1] + off1;
        oB1[2] = bx1[2] + off1; oB1[3] = bx1[3] + off1;
        aR1 = (oB1[2] - oB1[0]) * (oB1[3] - oB1[1]);
        ob[tid * 4 + 0] = oB0[0]; ob[tid * 4 + 1] = oB0[1];
        ob[tid * 4 + 2] = oB0[2]; ob[tid * 4 + 3] = oB0[3];
        ob[(tid + 1024) * 4 + 0] = oB1[0]; ob[(tid + 1024) * 4 + 1] = oB1[1];
        ob[(tid + 1024) * 4 + 2] = oB1[2]; ob[(tid + 1024) * 4 + 3] = oB1[3];
    }
    bool alive0 = val0, alive1 = val1;
    __syncthreads();

    int i = -1, kc = 0;
    while (true) {
        int start = i + 1;
        if (start >= K) break;
        int w = start >> 6;
        u64 m = mask[w] & (~0ULL << (start & 63));
        if (m == 0ULL) {
            u32 s = (w + 1 < 32) ? (wsum & (0xFFFFFFFFu << (w + 1))) : 0u;
            w = 32;
            while (s) {                      // executes once (summary exact post-barrier)
                int cw = __ffs(s) - 1;
                m = mask[cw];
                if (m) { w = cw; break; }
                s &= s - 1;
            }
        }
        if (w >= 32) break;
        i = (w << 6) + __ffsll((long long)m) - 1;
        ++kc;
        if (kc >= DET) break;                // later suppressions can't affect top-300
        double bi0 = ob[i * 4 + 0], bi1 = ob[i * 4 + 1];
        double bi2 = ob[i * 4 + 2], bi3 = ob[i * 4 + 3];
        double ai = (bi2 - bi0) * (bi3 - bi1);
        {
            double w_ = fmax(fmin(bi2, oB0[2]) - fmax(bi0, oB0[0]), 0.0);
            double h_ = fmax(fmin(bi3, oB0[3]) - fmax(bi1, oB0[1]), 0.0);
            double inter = w_ * h_;
            bool sup = inter > 0.45 * (ai + aR0 - inter + 1e-7);   // == iou>0.45 (denom>0)
            if (alive0 && tid > i && sup) {
                alive0 = false;
                u64 bit = 1ULL << (tid & 63);
                u64 old = atomicAnd(&mask[tid >> 6], ~bit);
                if ((old & ~bit) == 0ULL) atomicAnd(&wsum, ~(1u << (tid >> 6)));
            }
        }
        {
            int sl = tid + 1024;
            double w_ = fmax(fmin(bi2, oB1[2]) - fmax(bi0, oB1[0]), 0.0);
            double h_ = fmax(fmin(bi3, oB1[3]) - fmax(bi1, oB1[1]), 0.0);
            double inter = w_ * h_;
            bool sup = inter > 0.45 * (ai + aR1 - inter + 1e-7);
            if (alive1 && sl > i && sup) {
                alive1 = false;
                u64 bit = 1ULL << (sl & 63);
                u64 old = atomicAnd(&mask[sl >> 6], ~bit);
                if ((old & ~bit) == 0ULL) atomicAnd(&wsum, ~(1u << (sl >> 6)));
            }
        }
        __syncthreads();
    }
    __syncthreads();

    if (tid == 0) {
        int s = 0;
        for (int wv = 0; wv < 32; ++wv) { wpfx[wv] = s; s += __popcll(mask[wv]); }
        wpfx[32] = s;
    }
    __syncthreads();
    int total = wpfx[32]; if (total > DET) total = DET;

    float* bo  = out + (size_t)img * DET * 4;
    float* so_ = out + (size_t)B * DET * 4 + (size_t)img * DET;
    float* lo  = out + (size_t)B * DET * 5 + (size_t)img * DET;
    {
        int w = tid >> 6, bpos = tid & 63;
        if ((mask[w] >> bpos) & 1ULL) {
            int r = wpfx[w] + __popcll(mask[w] & ((1ULL << bpos) - 1ULL));
            if (r < DET) {
                bo[r * 4 + 0] = (float)bx0[0]; bo[r * 4 + 1] = (float)bx0[1];
                bo[r * 4 + 2] = (float)bx0[2]; bo[r * 4 + 3] = (float)bx0[3];
                so_[r] = (float)__longlong_as_double((long long)s0);
                lo[r] = (float)lab0;
            }
        }
    }
    {
        int sl = tid + 1024;
        int w = sl >> 6, bpos = sl & 63;
        if ((mask[w] >> bpos) & 1ULL) {
            int r = wpfx[w] + __popcll(mask[w] & ((1ULL << bpos) - 1ULL));
            if (r < DET) {
                bo[r * 4 + 0] = (float)bx1[0]; bo[r * 4 + 1] = (float)bx1[1];
                bo[r * 4 + 2] = (float)bx1[2]; bo[r * 4 + 3] = (float)bx1[3];
                so_[r] = (float)__longlong_as_double((long long)s1);
                lo[r] = (float)lab1;
            }
        }
    }
    if (tid >= total && tid < DET) {
        bo[tid * 4 + 0] = 0.f; bo[tid * 4 + 1] = 0.f;
        bo[tid * 4 + 2] = 0.f; bo[tid * 4 + 3] = 0.f;
        so_[tid] = -1.0f; lo[tid] = -1.0f;
    }
}

extern "C" void kernel_launch(void* const* d_in, const int* in_sizes, int n_in,
                              void* d_out, int out_size, void* d_ws, size_t ws_size,
                              hipStream_t stream) {
    const float* head = (const float*)d_in[0];   // [16,25200,85]
    const float* grid = (const float*)d_in[1];   // [25200,2]
    const float* ag   = (const float*)d_in[2];   // [25200,2]
    const float* stv  = (const float*)d_in[3];   // [25200,1]
    float* out = (float*)d_out;
    char* ws = (char*)d_ws;

    u64* sb     = (u64*)(ws + 0);                // 16*4096*8 = 524288
    u32* si     = (u32*)(ws + 524288);           // 262144
    int* alist  = (int*)(ws + 786432);           // 262144
    u32* cnt    = (u32*)(ws + 1048576);          // 64
    u32* cntA   = (u32*)(ws + 1048640);          // 64
    u64* cut    = (u64*)(ws + 1048704);          // 128
    u16* smax16 = (u16*)(ws + 1048832);          // 806400 -> end 1855232
    u32* phist  = (u32*)(ws + 1855232);          // B*hblk*2048*4

    // 64 partials/img needs ~10.3 MB of ws; fall back to 16 if scratch is small.
    int hblk = (ws_size >= (size_t)(1855232 + B * 64 * 2048 * 4)) ? 64 : 16;

    hipMemsetAsync(ws + 1048576, 0, 128, stream);   // cnt + cntA

    k_hist   <<<dim3(hblk, B), 256, 0, stream>>>(head, phist, smax16);
    k_redcut <<<B, 256, 0, stream>>>(phist, cut, hblk);
    k_screen <<<dim3((NA + 255) / 256, B), 256, 0, stream>>>(smax16, cut, cntA, alist);
    k_pairs  <<<dim3(32, B), 256, 0, stream>>>(head, cut, cntA, alist, cnt, sb, si);
    k_sort   <<<B, 1024, 0, stream>>>(cnt, sb, si);
    k_nms    <<<B, 1024, 0, stream>>>(head, grid, ag, stv, sb, si, out);
}

// Round 7
// 449.417 us; speedup vs baseline: 1.7219x; 1.3253x over previous
//
#include <hip/hip_runtime.h>
#include <hip/hip_bf16.h>

#define B    16
#define NA   25200
#define NCH  85
#define NCLS 80
#define K    2048
#define CAP  4096
#define ACAP 4096
#define DET  300
#define TILE 64
#define NTILES 394                     // ceil(25200/64)
#define PBLK 64                        // k_pairs blocks per image
#define LBUF 2304                      // k_pairs LDS buffer (2048 thresh + 256 max add)
#define SBASE  0x3FD0000000000000ULL   // bits of 0.25 (double)
#define SSHIFT 42                      // -> 2048 bins over (0.25, 1.0)

typedef unsigned long long u64;
typedef unsigned int u32;
typedef unsigned short u16;

__device__ __forceinline__ double dsig(float x) { return 1.0 / (1.0 + exp(-(double)x)); }
__device__ __forceinline__ float  fsig(float x) { return 1.0f / (1.0f + __expf(-x)); }

// ---- Pass 1: full sweep. Per-block partial histogram (plain stores) +
// per-anchor f32 max-score rounded UP to u16. 4 tasks/anchor (20 classes each).
__global__ void __launch_bounds__(256) k_hist(const float* __restrict__ head,
                                              u32* __restrict__ phist, u16* __restrict__ smax16) {
    __shared__ float rows[TILE * NCH];     // 21760 B
    __shared__ int h[2048];                // 8192 B
    __shared__ float smaxT[TILE][4];       // 1024 B
    int tid = threadIdx.x;
    int hblk = gridDim.x;
    for (int i = tid; i < 2048; i += 256) h[i] = 0;
    int img = blockIdx.y;
    const float* ibase = head + (size_t)img * NA * NCH;

    for (int tile = blockIdx.x; tile < NTILES; tile += hblk) {
        int a0 = tile * TILE;
        int na = NA - a0; if (na > TILE) na = TILE;      // 64 or 48 (na*85 %4==0)
        const float4* src = (const float4*)(ibase + (size_t)a0 * NCH);
        int nf4 = (na * NCH) >> 2;
        __syncthreads();                                 // prev tile fully consumed
        for (int i = tid; i < nf4; i += 256) ((float4*)rows)[i] = src[i];
        __syncthreads();
        for (int t = tid; t < 4 * na; t += 256) {        // 4 threads per anchor
            int a = t >> 2, q = t & 3;
            float fo = fsig(rows[a * NCH + 4]);
            float lm = 0.0f;
            if (fo > 0.25f) {                            // score <= sig(obj)
                int c0 = q * 20;
                for (int c = c0; c < c0 + 20; ++c) {
                    float sc = fo * fsig(rows[a * NCH + 5 + c]);
                    lm = fmaxf(lm, sc);
                    if (sc > 0.25f) {
                        u64 bits = (u64)__double_as_longlong((double)sc);
                        int bb = (int)((bits - SBASE) >> SSHIFT);
                        if (bb > 2047) bb = 2047;
                        atomicAdd(&h[bb], 1);
                    }
                }
            }
            smaxT[a][q] = lm;
        }
        __syncthreads();
        for (int t = tid; t < na; t += 256) {
            float m = fmaxf(fmaxf(smaxT[t][0], smaxT[t][1]), fmaxf(smaxT[t][2], smaxT[t][3]));
            u32 mb = __float_as_uint(m);
            smax16[(size_t)img * NA + a0 + t] = (u16)((mb + 0xFFFFu) >> 16);  // round UP
        }
    }
    __syncthreads();
    u32* dst = phist + ((size_t)img * hblk + blockIdx.x) * 2048;
    for (int i = tid; i < 2048; i += 256) dst[i] = (u32)h[i];
}

// ---- Pass 2: fused partial-hist reduce + cut-bin search (one block per image) ----
__global__ void __launch_bounds__(256) k_redcut(const u32* __restrict__ phist,
                                                u64* __restrict__ cut, int hblk) {
    __shared__ int h[2048];
    int img = blockIdx.x, tid = threadIdx.x;
    for (int bin = tid; bin < 2048; bin += 256) {
        u32 s = 0;
        for (int p = 0; p < hblk; ++p) s += phist[((size_t)img * hblk + p) * 2048 + bin];
        h[bin] = (int)s;
    }
    __syncthreads();
    if (tid < 64) {                       // wave 0 does the top-down scan
        int lane = tid;
        int cum = 0; u64 cb = 0;
        for (int ch = 0; ch < 32; ++ch) {
            int pfx = h[2047 - ch * 64 - lane];
            for (int d = 1; d < 64; d <<= 1) { int o = __shfl_up(pfx, d, 64); if (lane >= d) pfx += o; }
            u64 ball = __ballot(cum + pfx >= K);
            if (ball) {
                int fl = __ffsll((long long)ball) - 1;
                int bin = 2047 - ch * 64 - fl;
                cb = (bin >= 1) ? (SBASE + ((u64)(bin - 1) << SSHIFT)) : 0ULL;  // one-bin margin
                break;
            }
            cum += __shfl(pfx, 63, 64);
        }
        if (lane == 0) cut[img] = cb;
    }
}

// ---- Pass 3a: screen anchors by smax upper bound; compact survivor list ----
__global__ void __launch_bounds__(256) k_screen(const u16* __restrict__ smax16, const u64* __restrict__ cut,
                                                u32* __restrict__ cntA, int* __restrict__ alist) {
    __shared__ int lcnt, lbase, buf[256];
    int img = blockIdx.y;
    int a = blockIdx.x * 256 + threadIdx.x;
    if (threadIdx.x == 0) lcnt = 0;
    __syncthreads();
    u64 cutb = cut[img];
    float cutf = cutb ? (float)__longlong_as_double((long long)cutb) : 0.25f;
    float pre = fmaxf(0.2489f, cutf * 0.999f);
    if (a < NA) {
        float fup = __uint_as_float(((u32)smax16[(size_t)img * NA + a]) << 16);
        if (fup >= pre) buf[atomicAdd(&lcnt, 1)] = a;
    }
    __syncthreads();
    if (threadIdx.x == 0 && lcnt) lbase = atomicAdd(&cntA[img], (u32)lcnt);
    __syncthreads();
    for (int i = threadIdx.x; i < lcnt; i += 256) {
        int pos = lbase + i;
        if (pos < ACAP) alist[img * ACAP + pos] = buf[i];
    }
}

// ---- Pass 3b: pairs with per-block LDS compaction; ~2 global atomics/block
// (vs 1/survivor: the 16 cnt[] words share one line -> atomic serialization). ----
__global__ void __launch_bounds__(256) k_pairs(const float* __restrict__ head, const u64* __restrict__ cut,
                                               const u32* __restrict__ cntA, const int* __restrict__ alist,
                                               u32* __restrict__ cnt, u64* __restrict__ sb, u32* __restrict__ si) {
    __shared__ u64 lsb[LBUF];
    __shared__ u32 lsi[LBUF];
    __shared__ u32 lcnt, lbase;
    int img = blockIdx.y;
    int tid = threadIdx.x;
    u64 cutb = cut[img];
    float cutf = cutb ? (float)__longlong_as_double((long long)cutb) : 0.25f;
    float pre = fmaxf(0.2489f, cutf * 0.999f);
    int nsur = (int)cntA[img]; if (nsur > ACAP) nsur = ACAP;
    int npairs = nsur * NCLS;
    u64* sbi = sb + (size_t)img * CAP;
    u32* sii = si + (size_t)img * CAP;
    const float* ibase = head + (size_t)img * NA * NCH;
    if (tid == 0) lcnt = 0;
    __syncthreads();

    int base = blockIdx.x * 256;
    int ntrip = (npairs > base) ? (npairs - base + PBLK * 256 - 1) / (PBLK * 256) : 0;
    for (int t = 0; t < ntrip; ++t) {
        int p = base + tid + t * PBLK * 256;
        if (p < npairs) {
            int ai = (int)((u32)p / NCLS);
            int c  = p - ai * NCLS;
            int a  = alist[img * ACAP + ai];
            const float* row = ibase + (size_t)a * NCH;
            float o = row[4], cl = row[5 + c];
            float s32 = fsig(o) * fsig(cl);
            if (s32 >= pre) {
                double sc = dsig(o) * dsig(cl);        // exact f64 decision
                if (sc > 0.25) {
                    u64 bits = (u64)__double_as_longlong(sc);
                    if (bits >= cutb) {
                        u32 pos = atomicAdd(&lcnt, 1u); // LDS atomic
                        if (pos < LBUF) { lsb[pos] = bits; lsi[pos] = (u32)(a * NCLS + c); }
                    }
                }
            }
        }
        __syncthreads();
        if (lcnt >= 2048) {                            // flush (room for next trip)
            u32 n = lcnt; if (n > LBUF) n = LBUF;
            if (tid == 0) lbase = atomicAdd(&cnt[img], n);
            __syncthreads();
            for (u32 i = tid; i < n; i += 256) {
                u32 pos = lbase + i;
                if (pos < CAP) { sbi[pos] = lsb[i]; sii[pos] = lsi[i]; }
            }
            __syncthreads();
            if (tid == 0) lcnt = 0;
            __syncthreads();
        }
    }
    u32 n = lcnt; if (n > LBUF) n = LBUF;
    if (n) {
        if (tid == 0) lbase = atomicAdd(&cnt[img], n);
        __syncthreads();
        for (u32 i = tid; i < n; i += 256) {
            u32 pos = lbase + i;
            if (pos < CAP) { sbi[pos] = lsb[i]; sii[pos] = lsi[i]; }
        }
    }
}

// ---- Pass 4 (fused): LDS bitonic sort -> regs -> decode (f64) -> LDS offset
// boxes -> bitmask greedy NMS (word-summary scan, mul-compare IoU) -> emit.
// 512 threads, 4 slots/thread. SA/SI alias the ob region (sort ends first). ----
__global__ void __launch_bounds__(512) k_snms(const float* __restrict__ head,
        const float* __restrict__ grid, const float* __restrict__ ag, const float* __restrict__ stv,
        const u32* __restrict__ cntArr, const u64* __restrict__ sb, const u32* __restrict__ si,
        float* __restrict__ out) {
    __shared__ double ob[K * 4];      // 65536 B (sort phase: SA@0 32KB, SI@32KB 16KB)
    __shared__ u64 mask[32];
    __shared__ u32 wsum;
    __shared__ double red[8];
    __shared__ double s_offb;
    __shared__ int wpfx[33];

    int img = blockIdx.x;
    int tid = threadIdx.x;
    u64* SA = (u64*)ob;
    u32* SI = (u32*)(ob + K * 2);
    const u64* A = sb + (size_t)img * CAP;
    const u32* I = si + (size_t)img * CAP;

    // --- sort phase ---
    int cnt = (int)cntArr[img]; if (cnt > CAP) cnt = CAP;
    int n = K; while (n < cnt) n <<= 1;            // 2048 or 4096
    for (int i = tid; i < n; i += 512) {
        SA[i] = (i < cnt) ? A[i] : 0ULL;
        SI[i] = (i < cnt) ? I[i] : 0xFFFFFFFFu;
    }
    __syncthreads();
    for (unsigned k = 2; k <= (unsigned)n; k <<= 1) {
        for (unsigned j = k >> 1; j > 0; j >>= 1) {
            for (unsigned i = tid; i < (unsigned)n; i += 512) {
                unsigned l = i ^ j;
                if (l > i) {
                    u64 s1 = SA[i], s2 = SA[l];
                    u32 i1 = SI[i], i2 = SI[l];
                    bool before = (s1 > s2) || (s1 == s2 && i1 < i2);
                    bool up = ((i & k) == 0);
                    if (up != before) { SA[i] = s2; SA[l] = s1; SI[i] = i2; SI[l] = i1; }
                }
            }
            __syncthreads();
        }
    }
    // extract top-2048 to registers (slot = q*512 + tid)
    u64 sv[4]; u32 fi[4];
    #pragma unroll
    for (int q = 0; q < 4; ++q) { sv[q] = SA[q * 512 + tid]; fi[q] = SI[q * 512 + tid]; }
    __syncthreads();                                // SA/SI dead; ob reusable

    // --- decode phase ---
    double bx[4][4];
    int lab[4];
    bool val[4];
    double lmax = -1e300;
    #pragma unroll
    for (int q = 0; q < 4; ++q) {
        val[q] = (sv[q] != 0ULL);
        bx[q][0] = bx[q][1] = bx[q][2] = bx[q][3] = 0.0;
        lab[q] = 0;
        if (val[q]) {
            int a = (int)(fi[q] / NCLS);
            lab[q] = (int)(fi[q] % NCLS);
            const float* row = head + ((size_t)img * NA + a) * NCH;
            double p0 = dsig(row[0]), p1 = dsig(row[1]), p2 = dsig(row[2]), p3 = dsig(row[3]);
            double st = (double)stv[a];
            double xc = (p0 * 2.0 - 0.5 + (double)grid[a * 2 + 0]) * st;
            double yc = (p1 * 2.0 - 0.5 + (double)grid[a * 2 + 1]) * st;
            double w = p2 * 2.0; w = (w * w) * (double)ag[a * 2 + 0];
            double h = p3 * 2.0; h = (h * h) * (double)ag[a * 2 + 1];
            bx[q][0] = xc - w * 0.5; bx[q][1] = yc - h * 0.5;
            bx[q][2] = xc + w * 0.5; bx[q][3] = yc + h * 0.5;
            lmax = fmax(lmax, fmax(fmax(bx[q][0], bx[q][1]), fmax(bx[q][2], bx[q][3])));
        }
    }
    for (int d = 1; d < 64; d <<= 1) lmax = fmax(lmax, __shfl_xor(lmax, d, 64));
    if ((tid & 63) == 0) red[tid >> 6] = lmax;
    #pragma unroll
    for (int q = 0; q < 4; ++q) {
        u64 bm = __ballot(val[q]);
        if ((tid & 63) == 0) mask[q * 8 + (tid >> 6)] = bm;
    }
    if (tid == 0) wsum = 0;
    __syncthreads();
    if (tid < 32) { if (mask[tid]) atomicOr(&wsum, 1u << tid); }
    if (tid == 0) {
        double m = red[0];
        for (int wv = 1; wv < 8; ++wv) m = fmax(m, red[wv]);
        s_offb = m + 1.0;                            // (max(cand)+1), np-exact
    }
    __syncthreads();
    double offb = s_offb;

    double oB[4][4], aR[4];
    #pragma unroll
    for (int q = 0; q < 4; ++q) {
        double off = offb * (double)lab[q];
        oB[q][0] = bx[q][0] + off; oB[q][1] = bx[q][1] + off;
        oB[q][2] = bx[q][2] + off; oB[q][3] = bx[q][3] + off;
        aR[q] = (oB[q][2] - oB[q][0]) * (oB[q][3] - oB[q][1]);
        int slot = q * 512 + tid;
        ob[slot * 4 + 0] = oB[q][0]; ob[slot * 4 + 1] = oB[q][1];
        ob[slot * 4 + 2] = oB[q][2]; ob[slot * 4 + 3] = oB[q][3];
    }
    bool alive[4];
    #pragma unroll
    for (int q = 0; q < 4; ++q) alive[q] = val[q];
    __syncthreads();

    // --- greedy NMS ---
    int i = -1, kc = 0;
    while (true) {
        int start = i + 1;
        if (start >= K) break;
        int w = start >> 6;
        u64 m = mask[w] & (~0ULL << (start & 63));
        if (m == 0ULL) {
            u32 s = (w + 1 < 32) ? (wsum & (0xFFFFFFFFu << (w + 1))) : 0u;
            w = 32;
            while (s) {
                int cw = __ffs(s) - 1;
                m = mask[cw];
                if (m) { w = cw; break; }
                s &= s - 1;
            }
        }
        if (w >= 32) break;
        i = (w << 6) + __ffsll((long long)m) - 1;
        ++kc;
        if (kc >= DET) break;                 // later suppressions can't affect top-300
        double bi0 = ob[i * 4 + 0], bi1 = ob[i * 4 + 1];
        double bi2 = ob[i * 4 + 2], bi3 = ob[i * 4 + 3];
        double ai = (bi2 - bi0) * (bi3 - bi1);
        #pragma unroll
        for (int q = 0; q < 4; ++q) {
            int slot = q * 512 + tid;
            double w_ = fmax(fmin(bi2, oB[q][2]) - fmax(bi0, oB[q][0]), 0.0);
            double h_ = fmax(fmin(bi3, oB[q][3]) - fmax(bi1, oB[q][1]), 0.0);
            double inter = w_ * h_;
            bool sup = inter > 0.45 * (ai + aR[q] - inter + 1e-7);  // == iou>0.45
            if (alive[q] && slot > i && sup) {
                alive[q] = false;
                u64 bit = 1ULL << (slot & 63);
                u64 old = atomicAnd(&mask[slot >> 6], ~bit);
                if ((old & ~bit) == 0ULL) atomicAnd(&wsum, ~(1u << (slot >> 6)));
            }
        }
        __syncthreads();
    }
    __syncthreads();

    // --- emit ---
    if (tid == 0) {
        int s = 0;
        for (int wv = 0; wv < 32; ++wv) { wpfx[wv] = s; s += __popcll(mask[wv]); }
        wpfx[32] = s;
    }
    __syncthreads();
    int total = wpfx[32]; if (total > DET) total = DET;

    float* bo  = out + (size_t)img * DET * 4;
    float* so_ = out + (size_t)B * DET * 4 + (size_t)img * DET;
    float* lo  = out + (size_t)B * DET * 5 + (size_t)img * DET;
    #pragma unroll
    for (int q = 0; q < 4; ++q) {
        int slot = q * 512 + tid;
        int w = slot >> 6, bpos = slot & 63;
        if ((mask[w] >> bpos) & 1ULL) {
            int r = wpfx[w] + __popcll(mask[w] & ((1ULL << bpos) - 1ULL));
            if (r < DET) {
                bo[r * 4 + 0] = (float)bx[q][0]; bo[r * 4 + 1] = (float)bx[q][1];
                bo[r * 4 + 2] = (float)bx[q][2]; bo[r * 4 + 3] = (float)bx[q][3];
                so_[r] = (float)__longlong_as_double((long long)sv[q]);
                lo[r] = (float)lab[q];
            }
        }
    }
    if (tid >= total && tid < DET) {
        bo[tid * 4 + 0] = 0.f; bo[tid * 4 + 1] = 0.f;
        bo[tid * 4 + 2] = 0.f; bo[tid * 4 + 3] = 0.f;
        so_[tid] = -1.0f; lo[tid] = -1.0f;
    }
}

extern "C" void kernel_launch(void* const* d_in, const int* in_sizes, int n_in,
                              void* d_out, int out_size, void* d_ws, size_t ws_size,
                              hipStream_t stream) {
    const float* head = (const float*)d_in[0];   // [16,25200,85]
    const float* grid = (const float*)d_in[1];   // [25200,2]
    const float* ag   = (const float*)d_in[2];   // [25200,2]
    const float* stv  = (const float*)d_in[3];   // [25200,1]
    float* out = (float*)d_out;
    char* ws = (char*)d_ws;

    u64* sb     = (u64*)(ws + 0);                // 16*4096*8 = 524288
    u32* si     = (u32*)(ws + 524288);           // 262144
    int* alist  = (int*)(ws + 786432);           // 262144
    u32* cnt    = (u32*)(ws + 1048576);          // 64
    u32* cntA   = (u32*)(ws + 1048640);          // 64
    u64* cut    = (u64*)(ws + 1048704);          // 128
    u16* smax16 = (u16*)(ws + 1048832);          // 806400 -> end 1855232
    u32* phist  = (u32*)(ws + 1855232);          // B*hblk*2048*4

    // 64 partials/img needs ~10.3 MB of ws; fall back to 16 if scratch is small.
    int hblk = (ws_size >= (size_t)(1855232 + B * 64 * 2048 * 4)) ? 64 : 16;

    hipMemsetAsync(ws + 1048576, 0, 128, stream);   // cnt + cntA

    k_hist   <<<dim3(hblk, B), 256, 0, stream>>>(head, phist, smax16);
    k_redcut <<<B, 256, 0, stream>>>(phist, cut, hblk);
    k_screen <<<dim3((NA + 255) / 256, B), 256, 0, stream>>>(smax16, cut, cntA, alist);
    k_pairs  <<<dim3(PBLK, B), 256, 0, stream>>>(head, cut, cntA, alist, cnt, sb, si);
    k_snms   <<<B, 512, 0, stream>>>(head, grid, ag, stv, cnt, sb, si, out);
}